// Round 14
// baseline (144.673 us; speedup 1.0000x reference)
//
#include <hip/hip_runtime.h>
#include <math.h>

// Problem constants
constexpr int S_    = 4096;
constexpr int Dm    = 896;
constexpr int NHd   = 14;
constexpr int NKVh  = 2;
constexpr int HDim  = 64;
constexpr int NQ    = NHd * HDim;        // 896
constexpr int NK    = NKVh * HDim;       // 128
constexpr int NQK   = NQ + NK;           // 1024 (qk buffer row stride)
constexpr int GROUPS = NHd / NKVh;       // 7
constexpr float L2B   = 19.9315685693241740873f;  // log2(1e6)
constexpr float LOG2E = 1.44269504088896340736f;

constexpr int NUNITS = 560;              // 40 chunks x 14 heads (QBLK=256)

typedef __attribute__((ext_vector_type(8)))  short bf16x8;
typedef __attribute__((ext_vector_type(4)))  short bf16x4;
typedef __attribute__((ext_vector_type(4)))  float f32x4;
typedef __attribute__((ext_vector_type(16))) float f32x16;
typedef __attribute__((ext_vector_type(4)))  int   i32x4;

__device__ __forceinline__ short f2bf(float f) {   // RNE float->bf16
  unsigned u = __builtin_bit_cast(unsigned, f);
  unsigned r = (u + 0x7FFFu + ((u >> 16) & 1u)) >> 16;
  return (short)r;
}
__device__ __forceinline__ float bf2f(short s) {
  return __builtin_bit_cast(float, ((unsigned)(unsigned short)s) << 16);
}

__device__ __forceinline__ unsigned cvtpk(float lo, float hi) {  // 2xf32 -> packed bf16
  unsigned r;
  asm("v_cvt_pk_bf16_f32 %0, %1, %2" : "=v"(r) : "v"(lo), "v"(hi));
  return r;
}

// async global->LDS, 16 bytes per lane; lds dest wave-uniform (HW adds lane*16)
__device__ __forceinline__ void gload16(const void* g, void* l) {
  __builtin_amdgcn_global_load_lds(
      (const __attribute__((address_space(1))) unsigned int*)g,
      (__attribute__((address_space(3))) unsigned int*)l, 16, 0, 0);
}

// ---------------------------------------------------------------------------
// Prep (fused): blocks 0..1791 cvt hs f32->bf16; 1792..2303 RoPE tables;
// 2304..2751 weight transposes (f32 -> bf16, [896][N] -> [N][896]).
// ---------------------------------------------------------------------------
__global__ __launch_bounds__(256) void prep_all(
    const float* __restrict__ hs, short* __restrict__ hsb,
    float* __restrict__ cost, float* __restrict__ sint,
    const float* __restrict__ Wq, const float* __restrict__ Wk,
    const float* __restrict__ Wv, const float* __restrict__ Wo,
    short* __restrict__ wtq, short* __restrict__ wto)
{
  const int bid = blockIdx.x;
  const int tid = threadIdx.x;
  if (bid < 1792) {
    int idx = bid * 256 + tid;
    float4 a = ((const float4*)hs)[idx * 2];
    float4 b = ((const float4*)hs)[idx * 2 + 1];
    bf16x8 o;
    o[0] = f2bf(a.x); o[1] = f2bf(a.y); o[2] = f2bf(a.z); o[3] = f2bf(a.w);
    o[4] = f2bf(b.x); o[5] = f2bf(b.y); o[6] = f2bf(b.z); o[7] = f2bf(b.w);
    ((bf16x8*)hsb)[idx] = o;
    return;
  }
  if (bid < 2304) {
    int idx = (bid - 1792) * 256 + tid;   // m*32 + j
    int m = idx >> 5, j = idx & 31;
    float invf = exp2f(-(float)j * (L2B / 32.0f));
    float th = (float)m * invf;
    float s, c;
    sincosf(th, &s, &c);
    cost[idx] = c;
    sint[idx] = s;
    return;
  }
  // weight transpose: b2 = kt + 14*by
  __shared__ float t[64 * 68];
  const int b2 = bid - 2304;
  const int kt = b2 % 14;
  const int by = b2 / 14;

  const float* src; int srcN, nt; short* dst; int rowOff;
  if (by < 14)      { src = Wq; srcN = NQ; nt = by;      dst = wtq; rowOff = 0; }
  else if (by < 16) { src = Wk; srcN = NK; nt = by - 14; dst = wtq; rowOff = 896; }
  else if (by < 18) { src = Wv; srcN = NK; nt = by - 16; dst = wtq; rowOff = 1024; }
  else              { src = Wo; srcN = NQ; nt = by - 18; dst = wto; rowOff = 0; }

  #pragma unroll
  for (int i = 0; i < 4; i++) {
    int idx = tid + i * 256;
    int r = idx >> 4, c4 = (idx & 15) * 4;
    *(float4*)&t[r * 68 + c4] =
        *(const float4*)&src[(size_t)(kt * 64 + r) * srcN + nt * 64 + c4];
  }
  __syncthreads();
  const int nl = tid >> 2;
  const int kc = (tid & 3) * 16;
  bf16x8 o0, o1;
  #pragma unroll
  for (int i = 0; i < 8; i++) o0[i] = f2bf(t[(kc + i) * 68 + nl]);
  #pragma unroll
  for (int i = 0; i < 8; i++) o1[i] = f2bf(t[(kc + 8 + i) * 68 + nl]);
  short* dp = dst + (size_t)(rowOff + nt * 64 + nl) * 896 + kt * 64 + kc;
  *(bf16x8*)dp = o0;
  *(bf16x8*)(dp + 8) = o1;
}

// ---------------------------------------------------------------------------
// MFMA GEMM, 64x128 tile, BK=64, 4 waves (2x2: wave = 32 rows x 64 cols).
// Grid (M/64, N/128).  EPI==0: QKV epilogue (bias + RoPE; Q scaled by
// log2e/8); EPI==1: plain f32 store.
// ---------------------------------------------------------------------------
template<int EPI>
__global__ __launch_bounds__(256) void gemm64(
    const short* __restrict__ A, const short* __restrict__ Bt,
    const float* __restrict__ biasq, const float* __restrict__ biask,
    const float* __restrict__ biasv,
    const float* __restrict__ cost, const float* __restrict__ sint,
    short* __restrict__ qkb, short* __restrict__ vtb,
    float* __restrict__ outp)
{
  __shared__ short Als[64 * 64];    // 8 KB
  __shared__ short Bls[128 * 64];   // 16 KB
  const int tid = threadIdx.x;
  const int lane = tid & 63;
  const int w = tid >> 6;
  const int wm = w >> 1, wn = w & 1;
  const int r16 = lane & 15, rg = lane >> 4;
  const int bm = blockIdx.x, bn = blockIdx.y;

  const f32x4 zero4 = {0.f, 0.f, 0.f, 0.f};
  f32x4 acc[2][4];
  #pragma unroll
  for (int mt = 0; mt < 2; mt++)
    #pragma unroll
    for (int nt = 0; nt < 4; nt++) acc[mt][nt] = zero4;

  const int srow = (lane >> 3);
  const int scol = (lane & 7) * 8;

  for (int kt = 0; kt < 14; ++kt) {
    __syncthreads();
    #pragma unroll
    for (int i = 0; i < 2; i++) {                 // A: 8 chunks of 8 rows
      int c = w * 2 + i;
      int row = c * 8 + srow;
      gload16(A + (size_t)(bm * 64 + row) * 896 + kt * 64 + scol, &Als[c * 512]);
    }
    #pragma unroll
    for (int i = 0; i < 4; i++) {                 // B: 16 chunks of 8 rows
      int c = w * 4 + i;
      int row = c * 8 + srow;
      gload16(Bt + (size_t)(bn * 128 + row) * 896 + kt * 64 + scol, &Bls[c * 512]);
    }
    __syncthreads();

    bf16x8 af[2][2], bfr[4][2];
    #pragma unroll
    for (int mt = 0; mt < 2; mt++)
      #pragma unroll
      for (int ks = 0; ks < 2; ks++)
        af[mt][ks] = *(const bf16x8*)&Als[(wm * 32 + mt * 16 + r16) * 64 + ks * 32 + rg * 8];
    #pragma unroll
    for (int nt = 0; nt < 4; nt++)
      #pragma unroll
      for (int ks = 0; ks < 2; ks++)
        bfr[nt][ks] = *(const bf16x8*)&Bls[(wn * 64 + nt * 16 + r16) * 64 + ks * 32 + rg * 8];
    #pragma unroll
    for (int mt = 0; mt < 2; mt++)
      #pragma unroll
      for (int nt = 0; nt < 4; nt++)
        #pragma unroll
        for (int ks = 0; ks < 2; ks++)
          acc[mt][nt] = __builtin_amdgcn_mfma_f32_16x16x32_bf16(
              af[mt][ks], bfr[nt][ks], acc[mt][nt], 0, 0, 0);
  }

  if (EPI == 0) {
    const int nbase = bn * 128 + wn * 64;
    if (bn < 8) {
      const float scl = (bn < 7) ? (0.125f * LOG2E) : 1.0f;
      const float* bias = (bn < 7) ? biasq : (biask - 896);
      #pragma unroll
      for (int mt = 0; mt < 2; mt++) {
        const int m0 = bm * 64 + wm * 32 + mt * 16 + rg * 4;
        #pragma unroll
        for (int nt = 0; nt < 4; nt++) {
          int n = nbase + nt * 16 + r16;
          int j = n & 31;
          float sgn = (n & 32) ? 1.f : -1.f;
          float b0 = bias[n], b1 = bias[n ^ 32];
          #pragma unroll
          for (int r = 0; r < 4; r++) {
            int m = m0 + r;
            float c_ = cost[m * 32 + j], s_ = sint[m * 32 + j];
            float val = ((acc[mt][nt][r] + b0) * c_ +
                         sgn * (acc[mt][nt ^ 2][r] + b1) * s_) * scl;
            qkb[(size_t)m * NQK + n] = f2bf(val);
          }
        }
      }
    } else {
      #pragma unroll
      for (int mt = 0; mt < 2; mt++) {
        const int m0 = bm * 64 + wm * 32 + mt * 16 + rg * 4;
        #pragma unroll
        for (int nt = 0; nt < 4; nt++) {
          int vc = wn * 64 + nt * 16 + r16;
          float b0 = biasv[vc];
          bf16x4 pk;
          #pragma unroll
          for (int r = 0; r < 4; r++) pk[r] = f2bf(acc[mt][nt][r] + b0);
          *(bf16x4*)&vtb[(size_t)vc * S_ + m0] = pk;
        }
      }
    }
  } else {
    #pragma unroll
    for (int mt = 0; mt < 2; mt++) {
      const int m0 = bm * 64 + wm * 32 + mt * 16 + rg * 4;
      #pragma unroll
      for (int nt = 0; nt < 4; nt++) {
        int n = bn * 128 + wn * 64 + nt * 16 + r16;
        #pragma unroll
        for (int r = 0; r < 4; r++)
          outp[(size_t)(m0 + r) * NQ + n] = acc[mt][nt][r];
      }
    }
  }
}

// ---------------------------------------------------------------------------
// Flash attention v11: 8 waves x Mq=32 = QBLK=256 sharing ONE K/V stream.
// Per-wave math identical to v9 (32x32x16 MFMAs, in-register P via cvt_pk +
// permlane32_swap, l via ones-MFMA, defer-max). K/V dbuf 32.8 KB LDS.
// Grid 512 blocks x 512 thr (2 blocks/CU, 4 waves/SIMD). Unit table: per
// head 40 chunks (qt>=12: 4-way, 8-11: 3-way, 4-7: 2-way, else whole),
// all <=16 iters, descending. ci=0 partials in attnb in place; ci>=1 in
// orec (287 records in hsb+wtq, 49 spill past attnb).
// ---------------------------------------------------------------------------
__global__ __launch_bounds__(512, 4) void flash_mfma(
    const short* __restrict__ qkb, const short* __restrict__ vtb,
    short* __restrict__ attnb, short* __restrict__ orec1,
    short* __restrict__ orec2, float* __restrict__ mlrec,
    unsigned* __restrict__ cnt)
{
  __shared__ __align__(16) char lds[32768];   // 2 x (K 8KB | V 8KB)
  __shared__ int s_unit;

  const int tid  = threadIdx.x;
  const int lane = tid & 63;
  const int w    = tid >> 6;          // 0..7: q rows w*32..
  const int q32  = lane & 31;
  const int hi   = lane >> 5;

  // staging: one K chunk + one V chunk per thread (512 = 64 rows x 8 chunks)
  const int key = tid >> 3;           // 0..63 (K key row / V hd row)
  const int c8  = tid & 7;
  const int swz = (c8 ^ (key & 7)) << 4;

  bf16x8 ones;
  #pragma unroll
  for (int j = 0; j < 8; j++) ones[j] = (short)0x3F80;  // bf16(1.0)

  for (;;) {
    __syncthreads();                       // prev unit's LDS reads done
    if (tid == 0) s_unit = (int)atomicAdd(cnt, 1u);
    __syncthreads();
    const int u = s_unit;
    if (u >= NUNITS) break;

    const int e = u / 14;
    const int h = u - e * 14;
    int qt, ci, n;
    if (e < 16)      { qt = 15 - (e >> 2); ci = e & 3; n = 4; }
    else if (e < 28) { int f = e - 16; qt = 11 - f / 3; ci = f - 3 * (f / 3); n = 3; }
    else if (e < 36) { int f = e - 28; qt = 7 - (f >> 1); ci = f & 1; n = 2; }
    else             { qt = 39 - e; ci = 0; n = 1; }
    const int K  = 4 * (qt + 1);
    const int L  = (K + n - 1) / n;
    const int kt_lo = ci * L;
    const int kt_hi = (kt_lo + L < K) ? (kt_lo + L) : K;
    const int kv = h / GROUPS;
    const int q0 = qt * 256;
    const int kbase2 = (NQ + kv * HDim) * 2;
    const int qg = q0 + w * 32 + q32;   // this lane's q row

    // Q B-fragments: B[k][q], k = hi*8+j -> hd = ks*16 + hi*8 + j
    bf16x8 qf[4];
    {
      const short* qp = qkb + (size_t)qg * NQK + h * HDim + hi * 8;
      #pragma unroll
      for (int ks = 0; ks < 4; ++ks) qf[ks] = *(const bf16x8*)(qp + ks * 16);
    }

    f32x16 acc_o[2], acc_l;
    float m_run = 0.f;
    #pragma unroll
    for (int r = 0; r < 16; ++r) { acc_o[0][r] = 0.f; acc_o[1][r] = 0.f; acc_l[r] = 0.f; }

    // staging global sources (pre-swizzled chunk so LDS dest stays linear)
    const char* ksrc = (const char*)qkb + (size_t)(kt_lo * 64 + key) * 2048 + kbase2 + swz;
    const char* vsrc = (const char*)vtb + (size_t)(kv * 64 + key) * 8192 + (size_t)kt_lo * 128 + swz;

    // prologue: stage tile kt_lo into buffer 0 (wave w covers rows w*8..w*8+7)
    gload16(ksrc, lds + w * 1024);
    gload16(vsrc, lds + 8192 + w * 1024);
    ksrc += 131072;   // 64 keys * 2048 B
    vsrc += 128;      // 64 keys * 2 B

    for (int kt = kt_lo; kt < kt_hi; ++kt) {
      const int cur = (kt - kt_lo) & 1;
      asm volatile("s_waitcnt vmcnt(0)" ::: "memory");  // cur tile landed
      __builtin_amdgcn_s_barrier();                     // all waves off buf cur^1
      if (kt + 1 < kt_hi) {                             // prefetch next
        char* B = lds + ((cur ^ 1) << 14);
        gload16(ksrc, B + w * 1024);
        gload16(vsrc, B + 8192 + w * 1024);
        ksrc += 131072;
        vsrc += 128;
      }
      __builtin_amdgcn_sched_barrier(0);
      const char* KsB = lds + (cur << 14);
      const char* VtB = KsB + 8192;
      const int kb = kt * 64;

      // S^T = K Q^T : sc[t] = D[key = kb + t*32 + (reg&3)+8*(reg>>2)+4*hi][q = q32]
      f32x16 sc[2];
      #pragma unroll
      for (int r = 0; r < 16; ++r) { sc[0][r] = 0.f; sc[1][r] = 0.f; }
      #pragma unroll
      for (int t = 0; t < 2; ++t) {
        const int krow = t * 32 + q32;         // A-operand row for this lane
        #pragma unroll
        for (int ks = 0; ks < 4; ++ks) {
          bf16x8 kf = *(const bf16x8*)(KsB + krow * 128 + (((2 * ks + hi) ^ (krow & 7)) << 4));
          sc[t] = __builtin_amdgcn_mfma_f32_32x32x16_bf16(kf, qf[ks], sc[t], 0, 0, 0);
        }
      }

      // causal mask (wave-uniform trigger)
      if (kb + 63 > q0 + w * 32) {
        #pragma unroll
        for (int t = 0; t < 2; ++t)
          #pragma unroll
          for (int r = 0; r < 16; ++r) {
            int kg = kb + t * 32 + (r & 3) + 8 * (r >> 2) + 4 * hi;
            sc[t][r] = (kg > qg) ? -1e30f : sc[t][r];
          }
      }

      // row max (in-lane tree + cross-half permlane swap)
      f32x16 mm;
      #pragma unroll
      for (int r = 0; r < 16; ++r) mm[r] = fmaxf(sc[0][r], sc[1][r]);
      #pragma unroll
      for (int r = 0; r < 8; ++r) mm[r] = fmaxf(mm[r], mm[r + 8]);
      #pragma unroll
      for (int r = 0; r < 4; ++r) mm[r] = fmaxf(mm[r], mm[r + 4]);
      float pm = fmaxf(fmaxf(mm[0], mm[1]), fmaxf(mm[2], mm[3]));
      {
        float a = pm, b = pm;
        asm("v_permlane32_swap_b32 %0, %1" : "+v"(a), "+v"(b));
        pm = fmaxf(a, b);
      }

      if (!__all(pm <= m_run + 8.0f)) {      // defer-max
        float newm = fmaxf(m_run, pm);
        float scl = exp2f(m_run - newm);
        m_run = newm;
        acc_l[0] *= scl;
        #pragma unroll
        for (int r = 0; r < 16; ++r) { acc_o[0][r] *= scl; acc_o[1][r] *= scl; }
      }

      // P = exp2(S - m) in place
      #pragma unroll
      for (int t = 0; t < 2; ++t)
        #pragma unroll
        for (int r = 0; r < 16; ++r) sc[t][r] = exp2f(sc[t][r] - m_run);

      // pack to bf16 pairs
      unsigned U0[2][4], U1[2][4];
      #pragma unroll
      for (int t = 0; t < 2; ++t)
        #pragma unroll
        for (int a = 0; a < 4; ++a) {
          U0[t][a] = cvtpk(sc[t][4 * a],     sc[t][4 * a + 1]);
          U1[t][a] = cvtpk(sc[t][4 * a + 2], sc[t][4 * a + 3]);
        }

      // per 16-key slice: build P B-frag via permlane32_swap; PV + l MFMAs
      #pragma unroll
      for (int kp = 0; kp < 4; ++kp) {
        const int t = kp >> 1, c = kp & 1;
        unsigned x0 = U0[t][2 * c], y0 = U0[t][2 * c + 1];
        unsigned x1 = U1[t][2 * c], y1 = U1[t][2 * c + 1];
        asm("v_permlane32_swap_b32 %0, %1" : "+v"(x0), "+v"(y0));
        asm("v_permlane32_swap_b32 %0, %1" : "+v"(x1), "+v"(y1));
        i32x4 pi = {(int)x0, (int)x1, (int)y0, (int)y1};
        bf16x8 pf = __builtin_bit_cast(bf16x8, pi);
        acc_l = __builtin_amdgcn_mfma_f32_32x32x16_bf16(ones, pf, acc_l, 0, 0, 0);
        #pragma unroll
        for (int dt = 0; dt < 2; ++dt) {
          const int d = dt * 32 + q32;       // A-operand row (V^T row = head dim)
          bf16x8 vf = *(const bf16x8*)(VtB + d * 128 + (((2 * kp + hi) ^ (d & 7)) << 4));
          acc_o[dt] = __builtin_amdgcn_mfma_f32_32x32x16_bf16(vf, pf, acc_o[dt], 0, 0, 0);
        }
      }
    }

    // epilogue: O^T rows d = dt*32 + 8*rq + 4*hi + (reg&3), col q lane-local
    if (n == 1) {
      const float inv = 1.0f / acc_l[0];
      short* op = attnb + (size_t)qg * NQ + h * HDim + 4 * hi;
      #pragma unroll
      for (int dt = 0; dt < 2; ++dt)
        #pragma unroll
        for (int rq = 0; rq < 4; ++rq) {
          bf16x4 pk;
          pk[0] = f2bf(acc_o[dt][4 * rq]     * inv);
          pk[1] = f2bf(acc_o[dt][4 * rq + 1] * inv);
          pk[2] = f2bf(acc_o[dt][4 * rq + 2] * inv);
          pk[3] = f2bf(acc_o[dt][4 * rq + 3] * inv);
          *(bf16x4*)(op + dt * 32 + 8 * rq) = pk;
        }
    } else {
      const int qloc = w * 32 + q32;
      short* op;
      if (ci == 0) {
        op = attnb + (size_t)qg * NQ + h * HDim + 4 * hi;
      } else {
        int er = (qt < 8) ? (qt - 4)
               : (qt < 12) ? (4 + (qt - 8) * 2 + (ci - 1))
                           : (12 + (qt - 12) * 3 + (ci - 1));
        int er_g = h * 24 + er;
        short* ob = (er_g < 287) ? (orec1 + (size_t)er_g * 16384)
                                 : (orec2 + (size_t)(er_g - 287) * 16384);
        op = ob + (size_t)qloc * 64 + 4 * hi;
      }
      #pragma unroll
      for (int dt = 0; dt < 2; ++dt)
        #pragma unroll
        for (int rq = 0; rq < 4; ++rq) {
          bf16x4 pk;
          pk[0] = f2bf(acc_o[dt][4 * rq]);
          pk[1] = f2bf(acc_o[dt][4 * rq + 1]);
          pk[2] = f2bf(acc_o[dt][4 * rq + 2]);
          pk[3] = f2bf(acc_o[dt][4 * rq + 3]);
          *(bf16x4*)(op + dt * 32 + 8 * rq) = pk;
        }
      if (hi == 0) {
        int co = (qt < 8) ? ((qt - 4) * 2 + ci)
               : (qt < 12) ? (8 + (qt - 8) * 3 + ci)
                           : (20 + (qt - 12) * 4 + ci);
        float2 ml = {m_run, acc_l[0]};
        *(float2*)(mlrec + ((size_t)(h * 36 + co) * 256 + qloc) * 2) = ml;
      }
    }
  }
}

// ---------------------------------------------------------------------------
// Merge 2/3/4-way key-chunk partials for split tiles (qt>=4) -> attnb.
// grid 168 (= 14 heads x 12 tiles), 256 threads (1 per q-row).
// ---------------------------------------------------------------------------
__global__ __launch_bounds__(256) void merge_chunks(
    const short* __restrict__ orec1, const short* __restrict__ orec2,
    const float* __restrict__ mlrec, short* __restrict__ attnb)
{
  const int b = blockIdx.x;
  const int h = b / 12;
  const int qt = 4 + (b - h * 12);
  const int n = (qt < 8) ? 2 : (qt < 12) ? 3 : 4;
  const int qloc = threadIdx.x;
  const int q = qt * 256 + qloc;

  const int co0 = (qt < 8) ? ((qt - 4) * 2)
                : (qt < 12) ? (8 + (qt - 8) * 3)
                            : (20 + (qt - 12) * 4);
  const int er0 = (qt < 8) ? (qt - 4)
                : (qt < 12) ? (4 + (qt - 8) * 2)
                            : (12 + (qt - 12) * 3);
  const int er0_g = h * 24 + er0;

  float2 ml[4];
  #pragma unroll
  for (int ci = 0; ci < 4; ci++)
    ml[ci] = (ci < n)
        ? *(const float2*)(mlrec + ((size_t)(h * 36 + co0 + ci) * 256 + qloc) * 2)
        : float2{-3.0e38f, 0.f};

  float M = fmaxf(fmaxf(ml[0].x, ml[1].x), fmaxf(ml[2].x, ml[3].x));
  float s[4];
  float lsum = 0.f;
  #pragma unroll
  for (int ci = 0; ci < 4; ci++) {
    s[ci] = (ci < n) ? exp2f(ml[ci].x - M) : 0.f;
    lsum += s[ci] * ml[ci].y;
  }
  float inv = 1.0f / lsum;
  #pragma unroll
  for (int ci = 0; ci < 4; ci++) s[ci] *= inv;

  short* O0 = attnb + (size_t)q * NQ + h * HDim;           // chunk0 in place
  const short* Op[3];
  #pragma unroll
  for (int ci = 1; ci < 4; ci++) {
    int eg = er0_g + (ci - 1);
    const short* ob = (eg < 287) ? (orec1 + (size_t)eg * 16384)
                                 : (orec2 + (size_t)(eg - 287) * 16384);
    Op[ci - 1] = ob + (size_t)qloc * 64;
  }

  #pragma unroll
  for (int i = 0; i < 8; i++) {      // 8 x bf16x8 = all 64 head dims
    bf16x8 x0 = *(const bf16x8*)(O0 + i * 8);
    bf16x8 x1 = *(const bf16x8*)(Op[0] + i * 8);
    bf16x8 x2 = (n >= 3) ? *(const bf16x8*)(Op[1] + i * 8) : x1;
    bf16x8 x3 = (n >= 4) ? *(const bf16x8*)(Op[2] + i * 8) : x1;
    bf16x8 o;
    #pragma unroll
    for (int j = 0; j < 8; j++)
      o[j] = f2bf(s[0] * bf2f(x0[j]) + s[1] * bf2f(x1[j]) +
                  s[2] * bf2f(x2[j]) + s[3] * bf2f(x3[j]));
    *(bf16x8*)(O0 + i * 8) = o;
  }
}

// ---------------------------------------------------------------------------
extern "C" void kernel_launch(void* const* d_in, const int* in_sizes, int n_in,
                              void* d_out, int out_size, void* d_ws, size_t ws_size,
                              hipStream_t stream)
{
  const float* hs = (const float*)d_in[0];
  // d_in[1] = attention_mask (exactly causal; handled analytically)
  const float* Wq = (const float*)d_in[2];
  const float* bq = (const float*)d_in[3];
  const float* Wk = (const float*)d_in[4];
  const float* bk = (const float*)d_in[5];
  const float* Wv = (const float*)d_in[6];
  const float* bv = (const float*)d_in[7];
  const float* Wo = (const float*)d_in[8];

  short* hsb  = (short*)d_ws;                     // [4096][896]  bf16 (7.34 MB)
  short* wtq  = hsb + (size_t)S_ * Dm;            // [1152][896]  bf16 (2.06 MB)
  short* wto  = wtq + (size_t)1152 * 896;         // [896][896]   bf16
  float* cost = (float*)(wto + (size_t)896 * 896);// [4096][32]   f32
  float* sint = cost + (size_t)S_ * 32;           // [4096][32]   f32
  short* qkb  = (short*)(sint + (size_t)S_ * 32); // [4096][1024] bf16
  short* vtb  = qkb + (size_t)S_ * NQK;           // [128][4096]  bf16 (V^T)
  short* attnb= vtb + (size_t)NK * S_;            // [4096][896]  bf16
  float* out  = (float*)d_out;

  // flash scratch aliases regions dead during flash:
  short*    orec1 = hsb;             // 287 records x 32KB = exactly hsb+wtq
  float*    mlrec = cost;            // 504 chunk-ml x 2KB = 1.03 MB <= cost+sint
  unsigned* cnt   = (unsigned*)((char*)attnb + (size_t)S_ * NQ * 2);  // past attnb
  short*    orec2 = (short*)((char*)cnt + 4096);  // 49 spill records (1.6 MB)
                                     // total ws use 30.4 MB (33.6 MB proven, r1)

  hipLaunchKernelGGL(prep_all, dim3(2752), dim3(256), 0, stream,
                     hs, hsb, cost, sint, Wq, Wk, Wv, Wo, wtq, wto);
  hipLaunchKernelGGL((gemm64<0>), dim3(64, 9), dim3(256), 0, stream,
                     hsb, wtq, bq, bk, bv, cost, sint, qkb, vtb, (float*)nullptr);
  hipMemsetAsync(cnt, 0, 4, stream);
  hipLaunchKernelGGL(flash_mfma, dim3(512), dim3(512), 0, stream,
                     qkb, vtb, attnb, orec1, orec2, mlrec, cnt);
  hipLaunchKernelGGL(merge_chunks, dim3(168), dim3(256), 0, stream,
                     orec1, orec2, mlrec, attnb);
  hipLaunchKernelGGL((gemm64<1>), dim3(64, 7), dim3(256), 0, stream,
                     attnb, wto, bq, bk, bv, cost, sint,
                     (short*)nullptr, (short*)nullptr, out);
}

// Round 15
// 129.712 us; speedup vs baseline: 1.1153x; 1.1153x over previous
//
#include <hip/hip_runtime.h>
#include <math.h>

// Problem constants
constexpr int S_    = 4096;
constexpr int Dm    = 896;
constexpr int NHd   = 14;
constexpr int NKVh  = 2;
constexpr int HDim  = 64;
constexpr int NQ    = NHd * HDim;        // 896
constexpr int NK    = NKVh * HDim;       // 128
constexpr int NQK   = NQ + NK;           // 1024 (qk buffer row stride)
constexpr int GROUPS = NHd / NKVh;       // 7
constexpr float L2B   = 19.9315685693241740873f;  // log2(1e6)
constexpr float LOG2E = 1.44269504088896340736f;

constexpr int NUNITS = 952;              // 68 chunks x 14 heads (QBLK=128)

typedef __attribute__((ext_vector_type(8)))  short bf16x8;
typedef __attribute__((ext_vector_type(4)))  short bf16x4;
typedef __attribute__((ext_vector_type(4)))  float f32x4;
typedef __attribute__((ext_vector_type(16))) float f32x16;
typedef __attribute__((ext_vector_type(4)))  int   i32x4;

__device__ __forceinline__ short f2bf(float f) {   // RNE float->bf16
  unsigned u = __builtin_bit_cast(unsigned, f);
  unsigned r = (u + 0x7FFFu + ((u >> 16) & 1u)) >> 16;
  return (short)r;
}
__device__ __forceinline__ float bf2f(short s) {
  return __builtin_bit_cast(float, ((unsigned)(unsigned short)s) << 16);
}

__device__ __forceinline__ unsigned cvtpk(float lo, float hi) {  // 2xf32 -> packed bf16
  unsigned r;
  asm("v_cvt_pk_bf16_f32 %0, %1, %2" : "=v"(r) : "v"(lo), "v"(hi));
  return r;
}

// async global->LDS, 16 bytes per lane; lds dest wave-uniform (HW adds lane*16)
__device__ __forceinline__ void gload16(const void* g, void* l) {
  __builtin_amdgcn_global_load_lds(
      (const __attribute__((address_space(1))) unsigned int*)g,
      (__attribute__((address_space(3))) unsigned int*)l, 16, 0, 0);
}

// ---------------------------------------------------------------------------
// Prep (fused): blocks 0..1791 cvt hs f32->bf16; 1792..2303 RoPE tables;
// 2304..2751 weight transposes. Block 2751 also zeroes the work-queue
// counter (stream order: prep_all completes before flash launches).
// ---------------------------------------------------------------------------
__global__ __launch_bounds__(256) void prep_all(
    const float* __restrict__ hs, short* __restrict__ hsb,
    float* __restrict__ cost, float* __restrict__ sint,
    const float* __restrict__ Wq, const float* __restrict__ Wk,
    const float* __restrict__ Wv, const float* __restrict__ Wo,
    short* __restrict__ wtq, short* __restrict__ wto,
    unsigned* __restrict__ cnt)
{
  const int bid = blockIdx.x;
  const int tid = threadIdx.x;
  if (bid == 2751 && tid == 0) *cnt = 0u;
  if (bid < 1792) {
    int idx = bid * 256 + tid;
    float4 a = ((const float4*)hs)[idx * 2];
    float4 b = ((const float4*)hs)[idx * 2 + 1];
    bf16x8 o;
    o[0] = f2bf(a.x); o[1] = f2bf(a.y); o[2] = f2bf(a.z); o[3] = f2bf(a.w);
    o[4] = f2bf(b.x); o[5] = f2bf(b.y); o[6] = f2bf(b.z); o[7] = f2bf(b.w);
    ((bf16x8*)hsb)[idx] = o;
    return;
  }
  if (bid < 2304) {
    int idx = (bid - 1792) * 256 + tid;   // m*32 + j
    int m = idx >> 5, j = idx & 31;
    float invf = exp2f(-(float)j * (L2B / 32.0f));
    float th = (float)m * invf;
    float s, c;
    sincosf(th, &s, &c);
    cost[idx] = c;
    sint[idx] = s;
    return;
  }
  // weight transpose: b2 = kt + 14*by
  __shared__ float t[64 * 68];
  const int b2 = bid - 2304;
  const int kt = b2 % 14;
  const int by = b2 / 14;

  const float* src; int srcN, nt; short* dst; int rowOff;
  if (by < 14)      { src = Wq; srcN = NQ; nt = by;      dst = wtq; rowOff = 0; }
  else if (by < 16) { src = Wk; srcN = NK; nt = by - 14; dst = wtq; rowOff = 896; }
  else if (by < 18) { src = Wv; srcN = NK; nt = by - 16; dst = wtq; rowOff = 1024; }
  else              { src = Wo; srcN = NQ; nt = by - 18; dst = wto; rowOff = 0; }

  #pragma unroll
  for (int i = 0; i < 4; i++) {
    int idx = tid + i * 256;
    int r = idx >> 4, c4 = (idx & 15) * 4;
    *(float4*)&t[r * 68 + c4] =
        *(const float4*)&src[(size_t)(kt * 64 + r) * srcN + nt * 64 + c4];
  }
  __syncthreads();
  const int nl = tid >> 2;
  const int kc = (tid & 3) * 16;
  bf16x8 o0, o1;
  #pragma unroll
  for (int i = 0; i < 8; i++) o0[i] = f2bf(t[(kc + i) * 68 + nl]);
  #pragma unroll
  for (int i = 0; i < 8; i++) o1[i] = f2bf(t[(kc + 8 + i) * 68 + nl]);
  short* dp = dst + (size_t)(rowOff + nt * 64 + nl) * 896 + kt * 64 + kc;
  *(bf16x8*)dp = o0;
  *(bf16x8*)(dp + 8) = o1;
}

// ---------------------------------------------------------------------------
// MFMA GEMM, 64x128 tile, BK=64, 4 waves (2x2: wave = 32 rows x 64 cols).
// Grid (M/64, N/128).  EPI==0: QKV epilogue (bias + RoPE; Q scaled by
// log2e/8); EPI==1: plain f32 store.
// ---------------------------------------------------------------------------
template<int EPI>
__global__ __launch_bounds__(256) void gemm64(
    const short* __restrict__ A, const short* __restrict__ Bt,
    const float* __restrict__ biasq, const float* __restrict__ biask,
    const float* __restrict__ biasv,
    const float* __restrict__ cost, const float* __restrict__ sint,
    short* __restrict__ qkb, short* __restrict__ vtb,
    float* __restrict__ outp)
{
  __shared__ short Als[64 * 64];    // 8 KB
  __shared__ short Bls[128 * 64];   // 16 KB
  const int tid = threadIdx.x;
  const int lane = tid & 63;
  const int w = tid >> 6;
  const int wm = w >> 1, wn = w & 1;
  const int r16 = lane & 15, rg = lane >> 4;
  const int bm = blockIdx.x, bn = blockIdx.y;

  const f32x4 zero4 = {0.f, 0.f, 0.f, 0.f};
  f32x4 acc[2][4];
  #pragma unroll
  for (int mt = 0; mt < 2; mt++)
    #pragma unroll
    for (int nt = 0; nt < 4; nt++) acc[mt][nt] = zero4;

  const int srow = (lane >> 3);
  const int scol = (lane & 7) * 8;

  for (int kt = 0; kt < 14; ++kt) {
    __syncthreads();
    #pragma unroll
    for (int i = 0; i < 2; i++) {                 // A: 8 chunks of 8 rows
      int c = w * 2 + i;
      int row = c * 8 + srow;
      gload16(A + (size_t)(bm * 64 + row) * 896 + kt * 64 + scol, &Als[c * 512]);
    }
    #pragma unroll
    for (int i = 0; i < 4; i++) {                 // B: 16 chunks of 8 rows
      int c = w * 4 + i;
      int row = c * 8 + srow;
      gload16(Bt + (size_t)(bn * 128 + row) * 896 + kt * 64 + scol, &Bls[c * 512]);
    }
    __syncthreads();

    bf16x8 af[2][2], bfr[4][2];
    #pragma unroll
    for (int mt = 0; mt < 2; mt++)
      #pragma unroll
      for (int ks = 0; ks < 2; ks++)
        af[mt][ks] = *(const bf16x8*)&Als[(wm * 32 + mt * 16 + r16) * 64 + ks * 32 + rg * 8];
    #pragma unroll
    for (int nt = 0; nt < 4; nt++)
      #pragma unroll
      for (int ks = 0; ks < 2; ks++)
        bfr[nt][ks] = *(const bf16x8*)&Bls[(wn * 64 + nt * 16 + r16) * 64 + ks * 32 + rg * 8];
    #pragma unroll
    for (int mt = 0; mt < 2; mt++)
      #pragma unroll
      for (int nt = 0; nt < 4; nt++)
        #pragma unroll
        for (int ks = 0; ks < 2; ks++)
          acc[mt][nt] = __builtin_amdgcn_mfma_f32_16x16x32_bf16(
              af[mt][ks], bfr[nt][ks], acc[mt][nt], 0, 0, 0);
  }

  if (EPI == 0) {
    const int nbase = bn * 128 + wn * 64;
    if (bn < 8) {
      const float scl = (bn < 7) ? (0.125f * LOG2E) : 1.0f;
      const float* bias = (bn < 7) ? biasq : (biask - 896);
      #pragma unroll
      for (int mt = 0; mt < 2; mt++) {
        const int m0 = bm * 64 + wm * 32 + mt * 16 + rg * 4;
        #pragma unroll
        for (int nt = 0; nt < 4; nt++) {
          int n = nbase + nt * 16 + r16;
          int j = n & 31;
          float sgn = (n & 32) ? 1.f : -1.f;
          float b0 = bias[n], b1 = bias[n ^ 32];
          #pragma unroll
          for (int r = 0; r < 4; r++) {
            int m = m0 + r;
            float c_ = cost[m * 32 + j], s_ = sint[m * 32 + j];
            float val = ((acc[mt][nt][r] + b0) * c_ +
                         sgn * (acc[mt][nt ^ 2][r] + b1) * s_) * scl;
            qkb[(size_t)m * NQK + n] = f2bf(val);
          }
        }
      }
    } else {
      #pragma unroll
      for (int mt = 0; mt < 2; mt++) {
        const int m0 = bm * 64 + wm * 32 + mt * 16 + rg * 4;
        #pragma unroll
        for (int nt = 0; nt < 4; nt++) {
          int vc = wn * 64 + nt * 16 + r16;
          float b0 = biasv[vc];
          bf16x4 pk;
          #pragma unroll
          for (int r = 0; r < 4; r++) pk[r] = f2bf(acc[mt][nt][r] + b0);
          *(bf16x4*)&vtb[(size_t)vc * S_ + m0] = pk;
        }
      }
    }
  } else {
    #pragma unroll
    for (int mt = 0; mt < 2; mt++) {
      const int m0 = bm * 64 + wm * 32 + mt * 16 + rg * 4;
      #pragma unroll
      for (int nt = 0; nt < 4; nt++) {
        int n = bn * 128 + wn * 64 + nt * 16 + r16;
        #pragma unroll
        for (int r = 0; r < 4; r++)
          outp[(size_t)(m0 + r) * NQ + n] = acc[mt][nt][r];
      }
    }
  }
}

// ---------------------------------------------------------------------------
// Flash attention (v9 schedule, known-best ~79-80 us): 32x32x16 MFMAs, P
// fully in registers (cvt_pk + v_permlane32_swap), l via ones-MFMA,
// defer-max. QBLK=128 (4 waves x Mq=32), KBLK=64, K/V double-buffered via
// global_load_lds (32.8 KB LDS, 3 blocks/CU = 384 q-rows/CU). 768 persistent
// blocks, atomic unit queue.
// Probed-and-rejected: setprio (r10), 4 blocks/CU (r10), triple-buffer with
// counted vmcnt (r12), 8-wave QBLK=256 (r14) — the last three all induce L2
// write-amplification (WRITE_SIZE 16->34 MB) above ~384 q-rows/CU, or add
// overhead with no latency benefit (K/V loads are L2-hits, ~200cy, already
// covered by the dbuf window).
// ---------------------------------------------------------------------------
__global__ __launch_bounds__(256, 3) void flash_mfma(
    const short* __restrict__ qkb, const short* __restrict__ vtb,
    short* __restrict__ attnb, short* __restrict__ orec,
    float* __restrict__ mlrec, unsigned* __restrict__ cnt)
{
  __shared__ __align__(16) char lds[32768];   // 2 x (K 8KB | V 8KB)
  __shared__ int s_unit;

  const int tid  = threadIdx.x;
  const int lane = tid & 63;
  const int w    = tid >> 6;          // 0..3: q rows w*32..
  const int q32  = lane & 31;
  const int hi   = lane >> 5;

  // staging lane mapping (2 rows per thread for K and V)
  const int c8   = tid & 7;
  const int key0 = tid >> 3;          // 0..31
  const int key1 = key0 + 32;
  const int swz0 = (c8 ^ (key0 & 7)) << 4;
  const int swz1 = (c8 ^ (key1 & 7)) << 4;

  bf16x8 ones;
  #pragma unroll
  for (int j = 0; j < 8; j++) ones[j] = (short)0x3F80;  // bf16(1.0)

  for (;;) {
    __syncthreads();                       // prev unit's LDS reads done
    if (tid == 0) s_unit = (int)atomicAdd(cnt, 1u);
    __syncthreads();
    const int u = s_unit;
    if (u >= NUNITS) break;

    const int e = u / 14;
    const int h = u - e * 14;
    int qt, ci;
    if (e < 36)      { qt = 31 - e / 3; ci = e - (31 - qt) * 3; }
    else if (e < 60) { int f = e - 36; qt = 19 - (f >> 1); ci = f & 1; }
    else             { qt = 67 - e; ci = 0; }
    const int K  = 2 * (qt + 1);
    const int n  = (qt < 8) ? 1 : (qt < 20) ? 2 : 3;
    const int L  = (K + n - 1) / n;
    const int kt_lo = ci * L;
    const int kt_hi = (kt_lo + L < K) ? (kt_lo + L) : K;
    const int kv = h / GROUPS;
    const int q0 = qt * 128;
    const int kbase2 = (NQ + kv * HDim) * 2;
    const int qg = q0 + w * 32 + q32;   // this lane's q row (for B-cols & mask)

    // Q B-fragments: B[k][q], k = hi*8+j -> hd = ks*16 + hi*8 + j
    bf16x8 qf[4];
    {
      const short* qp = qkb + (size_t)qg * NQK + h * HDim + hi * 8;
      #pragma unroll
      for (int ks = 0; ks < 4; ++ks) qf[ks] = *(const bf16x8*)(qp + ks * 16);
    }

    f32x16 acc_o[2], acc_l;
    float m_run = 0.f;
    #pragma unroll
    for (int r = 0; r < 16; ++r) { acc_o[0][r] = 0.f; acc_o[1][r] = 0.f; acc_l[r] = 0.f; }

    // staging global sources (pre-swizzled chunk so LDS dest stays linear)
    const char* ksrc0 = (const char*)qkb + (size_t)(kt_lo * 64 + key0) * 2048 + kbase2 + swz0;
    const char* ksrc1 = (const char*)qkb + (size_t)(kt_lo * 64 + key1) * 2048 + kbase2 + swz1;
    const char* vsrc0 = (const char*)vtb + (size_t)(kv * 64 + key0) * 8192 + (size_t)kt_lo * 128 + swz0;
    const char* vsrc1 = (const char*)vtb + (size_t)(kv * 64 + key1) * 8192 + (size_t)kt_lo * 128 + swz1;

    // prologue: stage tile kt_lo into buffer 0
    gload16(ksrc0, lds + w * 1024);
    gload16(ksrc1, lds + 4096 + w * 1024);
    gload16(vsrc0, lds + 8192 + w * 1024);
    gload16(vsrc1, lds + 12288 + w * 1024);
    ksrc0 += 131072; ksrc1 += 131072;
    vsrc0 += 128;    vsrc1 += 128;

    for (int kt = kt_lo; kt < kt_hi; ++kt) {
      const int cur = (kt - kt_lo) & 1;
      asm volatile("s_waitcnt vmcnt(0)" ::: "memory");  // cur tile landed
      __builtin_amdgcn_s_barrier();                     // all waves off buf cur^1
      if (kt + 1 < kt_hi) {                             // prefetch next
        char* B = lds + ((cur ^ 1) << 14);
        gload16(ksrc0, B + w * 1024);
        gload16(ksrc1, B + 4096 + w * 1024);
        gload16(vsrc0, B + 8192 + w * 1024);
        gload16(vsrc1, B + 12288 + w * 1024);
        ksrc0 += 131072; ksrc1 += 131072;
        vsrc0 += 128;    vsrc1 += 128;
      }
      __builtin_amdgcn_sched_barrier(0);
      const char* KsB = lds + (cur << 14);
      const char* VtB = KsB + 8192;
      const int kb = kt * 64;

      // S^T = K Q^T : sc[t] = D[key = kb + t*32 + (reg&3)+8*(reg>>2)+4*hi][q = q32]
      f32x16 sc[2];
      #pragma unroll
      for (int r = 0; r < 16; ++r) { sc[0][r] = 0.f; sc[1][r] = 0.f; }
      #pragma unroll
      for (int t = 0; t < 2; ++t) {
        const int key = t * 32 + q32;          // A-operand row for this lane
        #pragma unroll
        for (int ks = 0; ks < 4; ++ks) {
          bf16x8 kf = *(const bf16x8*)(KsB + key * 128 + (((2 * ks + hi) ^ (key & 7)) << 4));
          sc[t] = __builtin_amdgcn_mfma_f32_32x32x16_bf16(kf, qf[ks], sc[t], 0, 0, 0);
        }
      }

      // causal mask (wave-uniform trigger)
      if (kb + 63 > q0 + w * 32) {
        #pragma unroll
        for (int t = 0; t < 2; ++t)
          #pragma unroll
          for (int r = 0; r < 16; ++r) {
            int key = kb + t * 32 + (r & 3) + 8 * (r >> 2) + 4 * hi;
            sc[t][r] = (key > qg) ? -1e30f : sc[t][r];
          }
      }

      // row max (in-lane tree + cross-half permlane swap)
      f32x16 mm;
      #pragma unroll
      for (int r = 0; r < 16; ++r) mm[r] = fmaxf(sc[0][r], sc[1][r]);
      #pragma unroll
      for (int r = 0; r < 8; ++r) mm[r] = fmaxf(mm[r], mm[r + 8]);
      #pragma unroll
      for (int r = 0; r < 4; ++r) mm[r] = fmaxf(mm[r], mm[r + 4]);
      float pm = fmaxf(fmaxf(mm[0], mm[1]), fmaxf(mm[2], mm[3]));
      {
        float a = pm, b = pm;
        asm("v_permlane32_swap_b32 %0, %1" : "+v"(a), "+v"(b));
        pm = fmaxf(a, b);
      }

      if (!__all(pm <= m_run + 8.0f)) {      // defer-max
        float newm = fmaxf(m_run, pm);
        float scl = exp2f(m_run - newm);
        m_run = newm;
        acc_l[0] *= scl;
        #pragma unroll
        for (int r = 0; r < 16; ++r) { acc_o[0][r] *= scl; acc_o[1][r] *= scl; }
      }

      // P = exp2(S - m) in place
      #pragma unroll
      for (int t = 0; t < 2; ++t)
        #pragma unroll
        for (int r = 0; r < 16; ++r) sc[t][r] = exp2f(sc[t][r] - m_run);

      // pack to bf16 pairs
      unsigned U0[2][4], U1[2][4];
      #pragma unroll
      for (int t = 0; t < 2; ++t)
        #pragma unroll
        for (int a = 0; a < 4; ++a) {
          U0[t][a] = cvtpk(sc[t][4 * a],     sc[t][4 * a + 1]);
          U1[t][a] = cvtpk(sc[t][4 * a + 2], sc[t][4 * a + 3]);
        }

      // per 16-key slice: build P B-frag via permlane32_swap; PV + l MFMAs
      #pragma unroll
      for (int kp = 0; kp < 4; ++kp) {
        const int t = kp >> 1, c = kp & 1;
        unsigned x0 = U0[t][2 * c], y0 = U0[t][2 * c + 1];
        unsigned x1 = U1[t][2 * c], y1 = U1[t][2 * c + 1];
        asm("v_permlane32_swap_b32 %0, %1" : "+v"(x0), "+v"(y0));
        asm("v_permlane32_swap_b32 %0, %1" : "+v"(x1), "+v"(y1));
        i32x4 pi = {(int)x0, (int)x1, (int)y0, (int)y1};
        bf16x8 pf = __builtin_bit_cast(bf16x8, pi);
        acc_l = __builtin_amdgcn_mfma_f32_32x32x16_bf16(ones, pf, acc_l, 0, 0, 0);
        #pragma unroll
        for (int dt = 0; dt < 2; ++dt) {
          const int d = dt * 32 + q32;       // A-operand row (V^T row = head dim)
          bf16x8 vf = *(const bf16x8*)(VtB + d * 128 + (((2 * kp + hi) ^ (d & 7)) << 4));
          acc_o[dt] = __builtin_amdgcn_mfma_f32_32x32x16_bf16(vf, pf, acc_o[dt], 0, 0, 0);
        }
      }
    }

    // epilogue: O^T rows d = dt*32 + 8*rq + 4*hi + (reg&3), col q lane-local
    if (n == 1) {
      const float inv = 1.0f / acc_l[0];
      short* op = attnb + (size_t)qg * NQ + h * HDim + 4 * hi;
      #pragma unroll
      for (int dt = 0; dt < 2; ++dt)
        #pragma unroll
        for (int rq = 0; rq < 4; ++rq) {
          bf16x4 pk;
          pk[0] = f2bf(acc_o[dt][4 * rq]     * inv);
          pk[1] = f2bf(acc_o[dt][4 * rq + 1] * inv);
          pk[2] = f2bf(acc_o[dt][4 * rq + 2] * inv);
          pk[3] = f2bf(acc_o[dt][4 * rq + 3] * inv);
          *(bf16x4*)(op + dt * 32 + 8 * rq) = pk;
        }
    } else {
      const int qloc = w * 32 + q32;
      short* op;
      if (ci == 0) {
        op = attnb + (size_t)qg * NQ + h * HDim + 4 * hi;
      } else {
        int er = (qt < 20) ? (h * 36 + (qt - 8))
                           : (h * 36 + 12 + (qt - 20) * 2 + (ci - 1));
        op = orec + (size_t)er * 8192 + (size_t)qloc * 64 + 4 * hi;
      }
      #pragma unroll
      for (int dt = 0; dt < 2; ++dt)
        #pragma unroll
        for (int rq = 0; rq < 4; ++rq) {
          bf16x4 pk;
          pk[0] = f2bf(acc_o[dt][4 * rq]);
          pk[1] = f2bf(acc_o[dt][4 * rq + 1]);
          pk[2] = f2bf(acc_o[dt][4 * rq + 2]);
          pk[3] = f2bf(acc_o[dt][4 * rq + 3]);
          *(bf16x4*)(op + dt * 32 + 8 * rq) = pk;
        }
      if (hi == 0) {
        int co = (qt < 20) ? (8 + (qt - 8) * 2 + ci) : (32 + (qt - 20) * 3 + ci);
        float2 ml = {m_run, acc_l[0]};
        *(float2*)(mlrec + ((size_t)(h * 68 + co) * 128 + qloc) * 2) = ml;
      }
    }
  }
}

// ---------------------------------------------------------------------------
// Merge 2- or 3-way key-chunk partials for split tiles (qt>=8) -> attnb.
// grid 336 (= 14 heads x 24 tiles), 128 threads (1 per q-row).
// ---------------------------------------------------------------------------
__global__ __launch_bounds__(128) void merge_chunks(
    const short* __restrict__ orec, const float* __restrict__ mlrec,
    short* __restrict__ attnb)
{
  const int b = blockIdx.x;
  const int h = b / 24;
  const int qt = 8 + (b - h * 24);
  const int n = (qt < 20) ? 2 : 3;
  const int qloc = threadIdx.x;
  const int q = qt * 128 + qloc;

  const int co0 = (qt < 20) ? (8 + (qt - 8) * 2) : (32 + (qt - 20) * 3);
  float2 ml0 = *(const float2*)(mlrec + ((size_t)(h * 68 + co0)     * 128 + qloc) * 2);
  float2 ml1 = *(const float2*)(mlrec + ((size_t)(h * 68 + co0 + 1) * 128 + qloc) * 2);
  float2 ml2 = (n == 3)
      ? *(const float2*)(mlrec + ((size_t)(h * 68 + co0 + 2) * 128 + qloc) * 2)
      : float2{-3.0e38f, 0.f};

  float M = fmaxf(fmaxf(ml0.x, ml1.x), ml2.x);
  float a0 = exp2f(ml0.x - M), a1 = exp2f(ml1.x - M);
  float a2 = (n == 3) ? exp2f(ml2.x - M) : 0.f;
  float inv = 1.0f / (a0 * ml0.y + a1 * ml1.y + a2 * ml2.y);
  float s0 = a0 * inv, s1 = a1 * inv, s2 = a2 * inv;

  const int er1 = (qt < 20) ? (h * 36 + (qt - 8)) : (h * 36 + 12 + (qt - 20) * 2);
  short* O0 = attnb + (size_t)q * NQ + h * HDim;           // chunk0 in place
  const short* O1 = orec + (size_t)er1 * 8192 + (size_t)qloc * 64;
  const short* O2 = (n == 3) ? (O1 + 8192) : O1;           // er1+1 record

  #pragma unroll
  for (int i = 0; i < 8; i++) {
    bf16x8 x0 = *(const bf16x8*)(O0 + i * 8);
    bf16x8 x1 = *(const bf16x8*)(O1 + i * 8);
    bf16x8 x2 = *(const bf16x8*)(O2 + i * 8);
    bf16x8 o;
    #pragma unroll
    for (int j = 0; j < 8; j++)
      o[j] = f2bf(s0 * bf2f(x0[j]) + s1 * bf2f(x1[j]) + s2 * bf2f(x2[j]));
    *(bf16x8*)(O0 + i * 8) = o;
  }
}

// ---------------------------------------------------------------------------
extern "C" void kernel_launch(void* const* d_in, const int* in_sizes, int n_in,
                              void* d_out, int out_size, void* d_ws, size_t ws_size,
                              hipStream_t stream)
{
  const float* hs = (const float*)d_in[0];
  // d_in[1] = attention_mask (exactly causal; handled analytically)
  const float* Wq = (const float*)d_in[2];
  const float* bq = (const float*)d_in[3];
  const float* Wk = (const float*)d_in[4];
  const float* bk = (const float*)d_in[5];
  const float* Wv = (const float*)d_in[6];
  const float* bv = (const float*)d_in[7];
  const float* Wo = (const float*)d_in[8];

  short* hsb  = (short*)d_ws;                     // [4096][896]  bf16 (7.34 MB)
  short* wtq  = hsb + (size_t)S_ * Dm;            // [1152][896]  bf16 (2.06 MB)
  short* wto  = wtq + (size_t)1152 * 896;         // [896][896]   bf16
  float* cost = (float*)(wto + (size_t)896 * 896);// [4096][32]   f32
  float* sint = cost + (size_t)S_ * 32;           // [4096][32]   f32
  short* qkb  = (short*)(sint + (size_t)S_ * 32); // [4096][1024] bf16
  short* vtb  = qkb + (size_t)S_ * NQK;           // [128][4096]  bf16 (V^T)
  short* attnb= vtb + (size_t)NK * S_;            // [4096][896]  bf16
  float* out  = (float*)d_out;

  // flash scratch aliases regions dead during flash:
  short*    orec  = hsb;             // 504 x 16384 B = 8.06 MB <= hsb+wtq (9.4 MB)
  float*    mlrec = cost;            // 952 x 128 x 2 f32 = 975 KB <= cost+sint
  unsigned* cnt   = (unsigned*)((char*)attnb + (size_t)S_ * NQ * 2);  // past attnb

  hipLaunchKernelGGL(prep_all, dim3(2752), dim3(256), 0, stream,
                     hs, hsb, cost, sint, Wq, Wk, Wv, Wo, wtq, wto, cnt);
  hipLaunchKernelGGL((gemm64<0>), dim3(64, 9), dim3(256), 0, stream,
                     hsb, wtq, bq, bk, bv, cost, sint, qkb, vtb, (float*)nullptr);
  hipLaunchKernelGGL(flash_mfma, dim3(768), dim3(256), 0, stream,
                     qkb, vtb, attnb, orec, mlrec, cnt);
  hipLaunchKernelGGL(merge_chunks, dim3(336), dim3(128), 0, stream,
                     orec, mlrec, attnb);
  hipLaunchKernelGGL((gemm64<1>), dim3(64, 7), dim3(256), 0, stream,
                     attnb, wto, bq, bk, bv, cost, sint,
                     (short*)nullptr, (short*)nullptr, out);
}